// Round 1
// baseline (3724.882 us; speedup 1.0000x reference)
//
#include <hip/hip_runtime.h>
#include <hip/hip_bf16.h>
#include <cstdint>
#include <cstddef>

// Problem dims (from setup_inputs)
#define BT 2048
#define V  32000
#define HS 2048
#define HT 4096

typedef float f32x4 __attribute__((ext_vector_type(4)));
typedef __bf16 bf16x8 __attribute__((ext_vector_type(8)));

__device__ __forceinline__ unsigned short f2bf(float f) {
    union { float f; unsigned u; } x; x.f = f;
    unsigned u = x.u;
    // round-to-nearest-even fp32 -> bf16
    unsigned r = (u + 0x7FFFu + ((u >> 16) & 1u)) >> 16;
    return (unsigned short)r;
}

// C[M][N] = A[M][K] @ W[N][K]^T   (A: BTxK row-major fp32, W: VxK row-major fp32)
// Block tile 128x128, BK=32, 256 threads = 4 waves, each wave a 64x64 quadrant.
template <int K>
__global__ __launch_bounds__(256, 2)
void gemm_bt(const float* __restrict__ A, const float* __restrict__ W,
             float* __restrict__ C) {
    // LDS tiles in bf16, row stride 40 elems (80 B): 16B-aligned rows, ~2-way banks
    __shared__ __align__(16) unsigned short As[128][40];
    __shared__ __align__(16) unsigned short Bs[128][40];

    const int tid  = threadIdx.x;
    const int m0   = blockIdx.x * 128;   // m-block fast-varying -> N-strip co-residency
    const int n0   = blockIdx.y * 128;
    const int wave = tid >> 6;
    const int lane = tid & 63;
    const int ln15 = lane & 15;
    const int q    = lane >> 4;          // quad 0..3
    const int wr   = wave >> 1;          // wave row 0..1
    const int wc   = wave & 1;           // wave col 0..1

    f32x4 acc[4][4];
#pragma unroll
    for (int i = 0; i < 4; ++i)
#pragma unroll
        for (int j = 0; j < 4; ++j)
            acc[i][j] = f32x4{0.f, 0.f, 0.f, 0.f};

    const int lr = tid >> 3;        // 0..31 (row within staging pass)
    const int lc = (tid & 7) * 4;   // 0..28 (col, float4 granularity)

    for (int k0 = 0; k0 < K; k0 += 32) {
#pragma unroll
        for (int p = 0; p < 4; ++p) {
            const int r = lr + p * 32;
            const float4 av = *(const float4*)&A[(size_t)(m0 + r) * K + k0 + lc];
            const float4 bv = *(const float4*)&W[(size_t)(n0 + r) * K + k0 + lc];
            As[r][lc + 0] = f2bf(av.x);
            As[r][lc + 1] = f2bf(av.y);
            As[r][lc + 2] = f2bf(av.z);
            As[r][lc + 3] = f2bf(av.w);
            Bs[r][lc + 0] = f2bf(bv.x);
            Bs[r][lc + 1] = f2bf(bv.y);
            Bs[r][lc + 2] = f2bf(bv.z);
            Bs[r][lc + 3] = f2bf(bv.w);
        }
        __syncthreads();

        bf16x8 af[4], bfr[4];
#pragma unroll
        for (int t = 0; t < 4; ++t) {
            af[t]  = *(const bf16x8*)&As[wr * 64 + t * 16 + ln15][q * 8];
            bfr[t] = *(const bf16x8*)&Bs[wc * 64 + t * 16 + ln15][q * 8];
        }
#pragma unroll
        for (int i = 0; i < 4; ++i)
#pragma unroll
            for (int j = 0; j < 4; ++j)
                acc[i][j] = __builtin_amdgcn_mfma_f32_16x16x32_bf16(
                    af[i], bfr[j], acc[i][j], 0, 0, 0);
        __syncthreads();
    }

    // Epilogue: C/D layout col=lane&15, row=q*4+reg
#pragma unroll
    for (int i = 0; i < 4; ++i) {
        const int row = m0 + wr * 64 + i * 16 + q * 4;
#pragma unroll
        for (int j = 0; j < 4; ++j) {
            const int col = n0 + wc * 64 + j * 16 + ln15;
#pragma unroll
            for (int r = 0; r < 4; ++r)
                C[(size_t)(row + r) * V + col] = acc[i][j][r];
        }
    }
}

// Per-row online logsumexp for student & teacher logits.
__global__ __launch_bounds__(256)
void row_stats(const float* __restrict__ S, const float* __restrict__ T,
               float* __restrict__ lse) {
    const int row = blockIdx.x;
    const int tid = threadIdx.x;
    const float* s = S + (size_t)row * V;
    const float* t = T + (size_t)row * V;

    float ms = -1e30f, ss = 0.f, mt = -1e30f, st = 0.f;
    for (int v = tid; v < V; v += 256) {
        float x = s[v];
        if (x > ms) { ss = ss * __expf(ms - x) + 1.f; ms = x; }
        else        { ss += __expf(x - ms); }
        float y = t[v];
        if (y > mt) { st = st * __expf(mt - y) + 1.f; mt = y; }
        else        { st += __expf(y - mt); }
    }

    __shared__ float rm[256], rs[256];
    // student
    rm[tid] = ms; rs[tid] = ss; __syncthreads();
    for (int off = 128; off > 0; off >>= 1) {
        if (tid < off) {
            float m1 = rm[tid], s1 = rs[tid];
            float m2 = rm[tid + off], s2 = rs[tid + off];
            float M = fmaxf(m1, m2);
            rm[tid] = M;
            rs[tid] = s1 * __expf(m1 - M) + s2 * __expf(m2 - M);
        }
        __syncthreads();
    }
    if (tid == 0) lse[row] = rm[0] + __logf(rs[0]);
    __syncthreads();
    // teacher
    rm[tid] = mt; rs[tid] = st; __syncthreads();
    for (int off = 128; off > 0; off >>= 1) {
        if (tid < off) {
            float m1 = rm[tid], s1 = rs[tid];
            float m2 = rm[tid + off], s2 = rs[tid + off];
            float M = fmaxf(m1, m2);
            rm[tid] = M;
            rs[tid] = s1 * __expf(m1 - M) + s2 * __expf(m2 - M);
        }
        __syncthreads();
    }
    if (tid == 0) lse[BT + row] = rm[0] + __logf(rs[0]);
}

// Per-row JSD + hard CE, atomically accumulated into out[0].
__global__ __launch_bounds__(256)
void loss_kernel(const float* __restrict__ S, const float* __restrict__ T,
                 const float* __restrict__ lse, const int* __restrict__ labels,
                 float* __restrict__ out) {
    const int row = blockIdx.x;
    const int tid = threadIdx.x;
    const float* s = S + (size_t)row * V;
    const float* t = T + (size_t)row * V;
    const float lseS = lse[row];
    const float lseT = lse[BT + row];

    float acc = 0.f;
    for (int v = tid; v < V; v += 256) {
        float ls = s[v] - lseS;
        float lt = t[v] - lseT;
        float ps = __expf(ls);
        float pt = __expf(lt);
        float lm = __logf(0.5f * (ps + pt));
        acc += ps * (ls - lm) + pt * (lt - lm);
    }

    __shared__ float red[256];
    red[tid] = acc; __syncthreads();
    for (int off = 128; off > 0; off >>= 1) {
        if (tid < off) red[tid] += red[tid + off];
        __syncthreads();
    }
    if (tid == 0) {
        const int lab = labels[row];
        float nll = 0.f;
        if (lab != -100) nll = lseS - s[lab];
        // total = 0.5*hard + 0.5*soft; hard = sum nll / BT;
        // soft = 0.5*(sum_row acc)/BT  -> per-row: (0.5*nll + 0.25*acc)/BT
        const float contrib = (0.5f * nll + 0.25f * red[0]) * (1.0f / (float)BT);
        atomicAdd(out, contrib);
    }
}

__global__ void zero_out(float* out) { out[0] = 0.f; }

extern "C" void kernel_launch(void* const* d_in, const int* in_sizes, int n_in,
                              void* d_out, int out_size, void* d_ws, size_t ws_size,
                              hipStream_t stream) {
    const float* s_in   = (const float*)d_in[0];  // (BT, HS)
    const float* s_w    = (const float*)d_in[1];  // (V, HS)
    const float* t_in   = (const float*)d_in[2];  // (BT, HT)
    const float* t_w    = (const float*)d_in[3];  // (V, HT)
    const int*   labels = (const int*)d_in[4];    // (BT,)
    float* out = (float*)d_out;

    char* ws = (char*)d_ws;
    const size_t logit_bytes = (size_t)BT * V * sizeof(float);  // 262,144,000
    float* s_logits = (float*)ws;
    float* t_logits = (float*)(ws + logit_bytes);
    float* lse      = (float*)(ws + 2 * logit_bytes);           // 2*BT floats

    zero_out<<<1, 1, 0, stream>>>(out);
    gemm_bt<HS><<<dim3(BT / 128, V / 128), 256, 0, stream>>>(s_in, s_w, s_logits);
    gemm_bt<HT><<<dim3(BT / 128, V / 128), 256, 0, stream>>>(t_in, t_w, t_logits);
    row_stats<<<BT, 256, 0, stream>>>(s_logits, t_logits, lse);
    loss_kernel<<<BT, 256, 0, stream>>>(s_logits, t_logits, lse, labels, out);
}

// Round 2
// 2060.361 us; speedup vs baseline: 1.8079x; 1.8079x over previous
//
#include <hip/hip_runtime.h>
#include <hip/hip_bf16.h>
#include <cstdint>
#include <cstddef>

// Problem dims (from setup_inputs)
#define BT 2048
#define V  32000
#define HS 2048
#define HT 4096

typedef float f32x4 __attribute__((ext_vector_type(4)));
typedef __bf16 bf16x8 __attribute__((ext_vector_type(8)));
typedef unsigned short u16x8 __attribute__((ext_vector_type(8)));

__device__ __forceinline__ unsigned short f2bf(float f) {
    union { float f; unsigned u; } x; x.f = f;
    unsigned u = x.u;
    unsigned r = (u + 0x7FFFu + ((u >> 16) & 1u)) >> 16;  // RNE fp32->bf16
    return (unsigned short)r;
}

// Async global->LDS, 16 B per lane. LDS dst is wave-uniform base + lane*16.
__device__ __forceinline__ void gload_lds16(const void* g, void* l) {
    __builtin_amdgcn_global_load_lds(
        (__attribute__((address_space(1))) void*)(void*)g,
        (__attribute__((address_space(3))) void*)l, 16, 0, 0);
}

// ---------------------------------------------------------------------------
// fp32 -> bf16 elementwise (8 elems / thread). Memory-bound.
__global__ __launch_bounds__(256)
void convert_bf16(const float* __restrict__ in, unsigned short* __restrict__ out,
                  int n8) {
    int i = blockIdx.x * 256 + threadIdx.x;
    if (i >= n8) return;
    const float4* p = (const float4*)in + (size_t)i * 2;
    float4 a = p[0], b = p[1];
    u16x8 r;
    r[0] = f2bf(a.x); r[1] = f2bf(a.y); r[2] = f2bf(a.z); r[3] = f2bf(a.w);
    r[4] = f2bf(b.x); r[5] = f2bf(b.y); r[6] = f2bf(b.z); r[7] = f2bf(b.w);
    ((u16x8*)out)[i] = r;
}

// ---------------------------------------------------------------------------
// FAST GEMM (bf16 inputs): C[M][N] = A[M][K] @ W[N][K]^T, fp32 out.
// m97 structure: 128x128 tile, BK=32, 4 waves x (64x64), global_load_lds w=16.
// LDS unpadded [128][32] bf16 (required by global_load_lds contiguity law);
// chunk-slot XOR swizzle (slot = chunk ^ (row&3)) cuts b128 read conflicts.
template <int K>
__global__ __launch_bounds__(256, 2)
void gemm_bf16(const unsigned short* __restrict__ A,
               const unsigned short* __restrict__ W,
               float* __restrict__ C) {
    __shared__ __align__(16) unsigned short As[128 * 32];
    __shared__ __align__(16) unsigned short Bs[128 * 32];

    const int tid  = threadIdx.x;
    const int m0   = blockIdx.x * 128;   // m fast-varying -> W-strip L2/LLC reuse
    const int n0   = blockIdx.y * 128;
    const int wave = tid >> 6;
    const int lane = tid & 63;
    const int ln15 = lane & 15;
    const int q    = lane >> 4;
    const int wr   = wave >> 1;
    const int wc   = wave & 1;

    // Staging: thread t -> row sr=t>>2 (and sr+64), LDS slot cs=t&3.
    // Global chunk fetched = cs ^ (sr&3)  (note (sr+64)&3 == sr&3).
    const int sr = tid >> 2;
    const int cs = tid & 3;
    const int cg = cs ^ (sr & 3);

    const unsigned short* ga0 = A + (size_t)(m0 + sr) * K + cg * 8;
    const unsigned short* ga1 = ga0 + (size_t)64 * K;
    const unsigned short* gb0 = W + (size_t)(n0 + sr) * K + cg * 8;
    const unsigned short* gb1 = gb0 + (size_t)64 * K;
    unsigned short* la0 = &As[sr * 32 + cs * 8];
    unsigned short* la1 = la0 + 64 * 32;
    unsigned short* lb0 = &Bs[sr * 32 + cs * 8];
    unsigned short* lb1 = lb0 + 64 * 32;

    f32x4 acc[4][4];
#pragma unroll
    for (int i = 0; i < 4; ++i)
#pragma unroll
        for (int j = 0; j < 4; ++j)
            acc[i][j] = f32x4{0.f, 0.f, 0.f, 0.f};

    // Fragment read slot: row R has R&3 == ln15&3; want chunk q -> slot q^(R&3).
    const int sl = q ^ (ln15 & 3);

    for (int k0 = 0; k0 < K; k0 += 32) {
        gload_lds16(ga0 + k0, la0);
        gload_lds16(ga1 + k0, la1);
        gload_lds16(gb0 + k0, lb0);
        gload_lds16(gb1 + k0, lb1);
        __syncthreads();   // drains vmcnt -> LDS valid

        bf16x8 af[4], bfv[4];
#pragma unroll
        for (int t = 0; t < 4; ++t) {
            af[t]  = *(const bf16x8*)&As[(wr * 64 + t * 16 + ln15) * 32 + sl * 8];
            bfv[t] = *(const bf16x8*)&Bs[(wc * 64 + t * 16 + ln15) * 32 + sl * 8];
        }
#pragma unroll
        for (int i = 0; i < 4; ++i)
#pragma unroll
            for (int j = 0; j < 4; ++j)
                acc[i][j] = __builtin_amdgcn_mfma_f32_16x16x32_bf16(
                    af[i], bfv[j], acc[i][j], 0, 0, 0);
        __syncthreads();
    }

    // C/D layout: col=lane&15, row=q*4+reg
#pragma unroll
    for (int i = 0; i < 4; ++i) {
        const int row = m0 + wr * 64 + i * 16 + q * 4;
#pragma unroll
        for (int j = 0; j < 4; ++j) {
            const int col = n0 + wc * 64 + j * 16 + ln15;
#pragma unroll
            for (int r = 0; r < 4; ++r)
                C[(size_t)(row + r) * V + col] = acc[i][j][r];
        }
    }
}

// ---------------------------------------------------------------------------
// FALLBACK GEMM (fp32 inputs, convert-in-kernel) — round-1 proven path,
// used only if ws_size can't hold the bf16 copies.
template <int K>
__global__ __launch_bounds__(256, 2)
void gemm_f32(const float* __restrict__ A, const float* __restrict__ W,
              float* __restrict__ C) {
    __shared__ __align__(16) unsigned short As[128][40];
    __shared__ __align__(16) unsigned short Bs[128][40];

    const int tid  = threadIdx.x;
    const int m0   = blockIdx.x * 128;
    const int n0   = blockIdx.y * 128;
    const int wave = tid >> 6;
    const int lane = tid & 63;
    const int ln15 = lane & 15;
    const int q    = lane >> 4;
    const int wr   = wave >> 1;
    const int wc   = wave & 1;

    f32x4 acc[4][4];
#pragma unroll
    for (int i = 0; i < 4; ++i)
#pragma unroll
        for (int j = 0; j < 4; ++j)
            acc[i][j] = f32x4{0.f, 0.f, 0.f, 0.f};

    const int lr = tid >> 3;
    const int lc = (tid & 7) * 4;

    for (int k0 = 0; k0 < K; k0 += 32) {
#pragma unroll
        for (int p = 0; p < 4; ++p) {
            const int r = lr + p * 32;
            const float4 av = *(const float4*)&A[(size_t)(m0 + r) * K + k0 + lc];
            const float4 bv = *(const float4*)&W[(size_t)(n0 + r) * K + k0 + lc];
            As[r][lc + 0] = f2bf(av.x); As[r][lc + 1] = f2bf(av.y);
            As[r][lc + 2] = f2bf(av.z); As[r][lc + 3] = f2bf(av.w);
            Bs[r][lc + 0] = f2bf(bv.x); Bs[r][lc + 1] = f2bf(bv.y);
            Bs[r][lc + 2] = f2bf(bv.z); Bs[r][lc + 3] = f2bf(bv.w);
        }
        __syncthreads();

        bf16x8 af[4], bfr[4];
#pragma unroll
        for (int t = 0; t < 4; ++t) {
            af[t]  = *(const bf16x8*)&As[wr * 64 + t * 16 + ln15][q * 8];
            bfr[t] = *(const bf16x8*)&Bs[wc * 64 + t * 16 + ln15][q * 8];
        }
#pragma unroll
        for (int i = 0; i < 4; ++i)
#pragma unroll
            for (int j = 0; j < 4; ++j)
                acc[i][j] = __builtin_amdgcn_mfma_f32_16x16x32_bf16(
                    af[i], bfr[j], acc[i][j], 0, 0, 0);
        __syncthreads();
    }

#pragma unroll
    for (int i = 0; i < 4; ++i) {
        const int row = m0 + wr * 64 + i * 16 + q * 4;
#pragma unroll
        for (int j = 0; j < 4; ++j) {
            const int col = n0 + wc * 64 + j * 16 + ln15;
#pragma unroll
            for (int r = 0; r < 4; ++r)
                C[(size_t)(row + r) * V + col] = acc[i][j][r];
        }
    }
}

// ---------------------------------------------------------------------------
// Fused per-row stats + loss. Phase 1: online logsumexp (branchless, float4).
// Phase 2: JSD accumulation + hard CE. One atomicAdd per row.
__device__ __forceinline__ void ol_update(float& m, float& s, float x) {
    float M = fmaxf(m, x);
    s = s * __expf(m - M) + __expf(x - M);
    m = M;
}

__global__ __launch_bounds__(256)
void stats_loss(const float* __restrict__ S, const float* __restrict__ T,
                const int* __restrict__ labels, float* __restrict__ out) {
    const int row = blockIdx.x;
    const int tid = threadIdx.x;
    const float4* s4 = (const float4*)(S + (size_t)row * V);
    const float4* t4 = (const float4*)(T + (size_t)row * V);
    const int NV4 = V / 4;  // 8000

    float ms = -1e30f, ss = 0.f, mt = -1e30f, st = 0.f;
    for (int i = tid; i < NV4; i += 256) {
        float4 a = s4[i];
        ol_update(ms, ss, a.x); ol_update(ms, ss, a.y);
        ol_update(ms, ss, a.z); ol_update(ms, ss, a.w);
        float4 b = t4[i];
        ol_update(mt, st, b.x); ol_update(mt, st, b.y);
        ol_update(mt, st, b.z); ol_update(mt, st, b.w);
    }

    __shared__ float rm[256], rs[256];
    // student lse
    rm[tid] = ms; rs[tid] = ss; __syncthreads();
    for (int off = 128; off > 0; off >>= 1) {
        if (tid < off) {
            float m1 = rm[tid], s1 = rs[tid];
            float m2 = rm[tid + off], s2 = rs[tid + off];
            float M = fmaxf(m1, m2);
            rm[tid] = M;
            rs[tid] = s1 * __expf(m1 - M) + s2 * __expf(m2 - M);
        }
        __syncthreads();
    }
    const float lseS = rm[0] + __logf(rs[0]);
    __syncthreads();
    // teacher lse
    rm[tid] = mt; rs[tid] = st; __syncthreads();
    for (int off = 128; off > 0; off >>= 1) {
        if (tid < off) {
            float m1 = rm[tid], s1 = rs[tid];
            float m2 = rm[tid + off], s2 = rs[tid + off];
            float M = fmaxf(m1, m2);
            rm[tid] = M;
            rs[tid] = s1 * __expf(m1 - M) + s2 * __expf(m2 - M);
        }
        __syncthreads();
    }
    const float lseT = rm[0] + __logf(rs[0]);
    __syncthreads();

    // Phase 2: JSD terms
    float acc = 0.f;
    for (int i = tid; i < NV4; i += 256) {
        float4 a = s4[i];
        float4 b = t4[i];
#pragma unroll
        for (int c = 0; c < 4; ++c) {
            float ls = ((const float*)&a)[c] - lseS;
            float lt = ((const float*)&b)[c] - lseT;
            float ps = __expf(ls);
            float pt = __expf(lt);
            float lm = __logf(0.5f * (ps + pt));
            acc += ps * (ls - lm) + pt * (lt - lm);
        }
    }
    rm[tid] = acc; __syncthreads();
    for (int off = 128; off > 0; off >>= 1) {
        if (tid < off) rm[tid] += rm[tid + off];
        __syncthreads();
    }
    if (tid == 0) {
        const int lab = labels[row];
        float nll = 0.f;
        if (lab != -100) nll = lseS - S[(size_t)row * V + lab];
        const float contrib = (0.5f * nll + 0.25f * rm[0]) * (1.0f / (float)BT);
        atomicAdd(out, contrib);
    }
}

__global__ void zero_out(float* out) { out[0] = 0.f; }

// ---------------------------------------------------------------------------
extern "C" void kernel_launch(void* const* d_in, const int* in_sizes, int n_in,
                              void* d_out, int out_size, void* d_ws, size_t ws_size,
                              hipStream_t stream) {
    const float* s_in   = (const float*)d_in[0];  // (BT, HS)
    const float* s_w    = (const float*)d_in[1];  // (V, HS)
    const float* t_in   = (const float*)d_in[2];  // (BT, HT)
    const float* t_w    = (const float*)d_in[3];  // (V, HT)
    const int*   labels = (const int*)d_in[4];    // (BT,)
    float* out = (float*)d_out;

    char* ws = (char*)d_ws;
    const size_t logit_bytes = (size_t)BT * V * sizeof(float);      // 262,144,000
    float* s_logits = (float*)ws;
    float* t_logits = (float*)(ws + logit_bytes);
    size_t off = 2 * logit_bytes;

    const size_t as_bytes = (size_t)BT * HS * 2;    //   8,388,608
    const size_t ws_bytes = (size_t)V  * HS * 2;    // 131,072,000
    const size_t at_bytes = (size_t)BT * HT * 2;    //  16,777,216
    const size_t wt_bytes = (size_t)V  * HT * 2;    // 262,144,000
    const size_t fast_total = off + as_bytes + ws_bytes + at_bytes + wt_bytes + 4096;

    zero_out<<<1, 1, 0, stream>>>(out);

    if (ws_size >= fast_total) {
        unsigned short* abf_s = (unsigned short*)(ws + off);  off += as_bytes;
        unsigned short* wbf_s = (unsigned short*)(ws + off);  off += ws_bytes;
        unsigned short* abf_t = (unsigned short*)(ws + off);  off += at_bytes;
        unsigned short* wbf_t = (unsigned short*)(ws + off);  off += wt_bytes;

        const int n8_as = BT * HS / 8, n8_ws = V * HS / 8;
        const int n8_at = BT * HT / 8, n8_wt = V * HT / 8;
        convert_bf16<<<(n8_as + 255) / 256, 256, 0, stream>>>(s_in, abf_s, n8_as);
        convert_bf16<<<(n8_ws + 255) / 256, 256, 0, stream>>>(s_w,  wbf_s, n8_ws);
        convert_bf16<<<(n8_at + 255) / 256, 256, 0, stream>>>(t_in, abf_t, n8_at);
        convert_bf16<<<(n8_wt + 255) / 256, 256, 0, stream>>>(t_w,  wbf_t, n8_wt);

        gemm_bf16<HS><<<dim3(BT / 128, V / 128), 256, 0, stream>>>(abf_s, wbf_s, s_logits);
        gemm_bf16<HT><<<dim3(BT / 128, V / 128), 256, 0, stream>>>(abf_t, wbf_t, t_logits);
    } else {
        gemm_f32<HS><<<dim3(BT / 128, V / 128), 256, 0, stream>>>(s_in, s_w, s_logits);
        gemm_f32<HT><<<dim3(BT / 128, V / 128), 256, 0, stream>>>(t_in, t_w, t_logits);
    }

    stats_loss<<<BT, 256, 0, stream>>>(s_logits, t_logits, labels, out);
}